// Round 7
// baseline (169.651 us; speedup 1.0000x reference)
//
#include <hip/hip_runtime.h>
#include <hip/hip_bf16.h>
#include <hip/hip_fp16.h>

typedef __attribute__((ext_vector_type(8))) short short8;     // bf16x8 frag
typedef __attribute__((ext_vector_type(8))) _Float16 half8;   // f16x8 frag
typedef __attribute__((ext_vector_type(4))) float f32x4;
typedef __attribute__((ext_vector_type(16))) float f32x16;
typedef __attribute__((ext_vector_type(4))) unsigned int uint4v;
typedef unsigned short u16;
typedef unsigned int u32;

#define LOG2E 1.44269504088896f

typedef const void __attribute__((address_space(1))) gvoid;
typedef void __attribute__((address_space(3))) lvoid;

__device__ __forceinline__ void gll16(const void* g, void* l) {
  __builtin_amdgcn_global_load_lds((gvoid*)g, (lvoid*)l, 16, 0, 0);
}

__device__ __forceinline__ u16 f2bf(float f) {
  u32 u = __builtin_bit_cast(u32, f);
  u += 0x7fffu + ((u >> 16) & 1u);
  return (u16)(u >> 16);
}
__device__ __forceinline__ u16 f2h(float f) {
  _Float16 h = (_Float16)f;
  return __builtin_bit_cast(u16, h);
}
__device__ __forceinline__ u32 cvtpk_bf16(float lo, float hi) {
  u32 r;
  asm("v_cvt_pk_bf16_f32 %0, %1, %2" : "=v"(r) : "v"(lo), "v"(hi));
  return r;
}

// ---------------------------------------------------------------------------
// K0: prep (unchanged).
// ---------------------------------------------------------------------------
__global__ void k_prep(const float* __restrict__ x,
                       const float* __restrict__ Wf, const float* __restrict__ bfp,
                       const float* __restrict__ Wg, const float* __restrict__ bgp,
                       const float* __restrict__ Wh, const float* __restrict__ bhp,
                       u16* __restrict__ xT, u16* __restrict__ Wall,
                       float* __restrict__ ball)
{
  int bid = blockIdx.x, t = threadIdx.x;
  if (bid < 1024) {
    __shared__ u16 tile[64][68];
    int b = bid >> 8, c0 = ((bid >> 6) & 3) << 6, n0 = (bid & 63) << 6;
#pragma unroll
    for (int r = 0; r < 4; ++r) {
      int cl = (t >> 4) + r * 16, nl = (t & 15) * 4;
      const float4 v = *(const float4*)&x[(size_t)(b * 256 + c0 + cl) * 4096 + n0 + nl];
      tile[cl][nl + 0] = f2h(v.x); tile[cl][nl + 1] = f2h(v.y);
      tile[cl][nl + 2] = f2h(v.z); tile[cl][nl + 3] = f2h(v.w);
    }
    __syncthreads();
#pragma unroll
    for (int r = 0; r < 4; ++r) {
      int nl = (t >> 4) + r * 16, cl = (t & 15) * 4;
      ushort4 o;
      o.x = tile[cl + 0][nl]; o.y = tile[cl + 1][nl];
      o.z = tile[cl + 2][nl]; o.w = tile[cl + 3][nl];
      *(ushort4*)&xT[(size_t)(b * 4096 + n0 + nl) * 256 + c0 + cl] = o;
    }
  } else {
    int wb = bid - 1024;                 // 0..79
    int e = wb * 1024 + t * 4;           // element in W_all (320*256)
    int r = e >> 8;
    const float* src = (r < 32) ? (Wf + e)
                     : (r < 64) ? (Wg + e - 32 * 256)
                                : (Wh + e - 64 * 256);
    float4 v = *(const float4*)src;
    float sc = (r >= 32 && r < 64) ? LOG2E : 1.0f;   // pre-scale Q path
    ushort4 o;
    o.x = f2h(v.x * sc); o.y = f2h(v.y * sc);
    o.z = f2h(v.z * sc); o.w = f2h(v.w * sc);
    *(ushort4*)&Wall[e] = o;
    if (wb == 0 && t < 80) {
#pragma unroll
      for (int i = 0; i < 4; ++i) {
        int idx = t * 4 + i;
        ball[idx] = (idx < 32) ? bfp[idx]
                  : (idx < 64) ? bgp[idx - 32] * LOG2E
                               : bhp[idx - 64];
      }
    }
  }
}

// ---------------------------------------------------------------------------
// K1: projections via f16 MFMA (unchanged).
// ---------------------------------------------------------------------------
__global__ __launch_bounds__(256, 4)
void k_proj(const u16* __restrict__ xT, const u16* __restrict__ Wall,
            const float* __restrict__ ball,
            u16* __restrict__ q, u16* __restrict__ kmat, u16* __restrict__ hbf)
{
  int bid = blockIdx.x, t = threadIdx.x;
  int w = t >> 6, l = t & 63, lg = l >> 4, li = l & 15;
  f32x4 Z = {0.f, 0.f, 0.f, 0.f};
  if (bid < 256) {        // ---- FG ----
    int b = bid >> 6, n0 = (bid & 63) << 6;
    int rbase = w * 16;
    half8 aw[8];
#pragma unroll
    for (int kk = 0; kk < 8; ++kk)
      aw[kk] = *(const half8*)&Wall[(rbase + li) * 256 + kk * 32 + lg * 8];
    float bias[4];
#pragma unroll
    for (int j = 0; j < 4; ++j) bias[j] = ball[rbase + 4 * lg + j];
#pragma unroll
    for (int nn = 0; nn < 4; ++nn) {
      int n = n0 + nn * 16 + li;
      f32x4 acc = Z;
#pragma unroll
      for (int kk = 0; kk < 8; ++kk) {
        half8 bx = *(const half8*)&xT[(size_t)(b * 4096 + n) * 256 + kk * 32 + lg * 8];
        acc = __builtin_amdgcn_mfma_f32_16x16x32_f16(aw[kk], bx, acc, 0, 0, 0);
      }
      ushort4 o;
      o.x = f2h(acc[0] + bias[0]); o.y = f2h(acc[1] + bias[1]);
      o.z = f2h(acc[2] + bias[2]); o.w = f2h(acc[3] + bias[3]);
      u16* dst = (rbase < 32)
               ? (kmat + (size_t)(b * 4096 + n) * 32 + rbase + 4 * lg)
               : (q    + (size_t)(b * 4096 + n) * 32 + (rbase - 32) + 4 * lg);
      *(ushort4*)dst = o;
    }
  } else {                // ---- H ----
    int hb = bid - 256;
    int b = hb >> 8, rt = (hb >> 6) & 3, n0 = (hb & 63) << 6;
    int r0 = 64 + rt * 64;
    int nbase = n0 + w * 16;
    half8 ax[8];
#pragma unroll
    for (int kk = 0; kk < 8; ++kk)
      ax[kk] = *(const half8*)&xT[(size_t)(b * 4096 + nbase + li) * 256 + kk * 32 + lg * 8];
#pragma unroll
    for (int rr = 0; rr < 4; ++rr) {
      int r = r0 + rr * 16 + li;
      f32x4 acc = Z;
#pragma unroll
      for (int kk = 0; kk < 8; ++kk) {
        half8 bw = *(const half8*)&Wall[r * 256 + kk * 32 + lg * 8];
        acc = __builtin_amdgcn_mfma_f32_16x16x32_f16(ax[kk], bw, acc, 0, 0, 0);
      }
      float bias = ball[r];
      ushort4 o;
      o.x = f2bf(acc[0] + bias); o.y = f2bf(acc[1] + bias);
      o.z = f2bf(acc[2] + bias); o.w = f2bf(acc[3] + bias);
      *(ushort4*)&hbf[(size_t)(b * 256 + r - 64) * 4096 + nbase + 4 * lg] = o;
    }
  }
}

// ---------------------------------------------------------------------------
// K2 v6b: M=64/block, 8 waves msub(2) x ch(4), counted-vmcnt 4-buf pipeline.
//  (R5 with the prologue K-buf1 LDS destination bug fixed.)
// ---------------------------------------------------------------------------
#define COMPUTE(BUFC)                                                          \
  {                                                                            \
    const int _bs = (BUFC) << 14;                                              \
    const int _bk = (BUFC) << 11;                                              \
    half8 k0 = *(const half8*)(raw + (ka0 | _bk));                             \
    half8 k1 = *(const half8*)(raw + (ka1 | _bk));                             \
    f32x16 sa = __builtin_amdgcn_mfma_f32_32x32x16_f16(k0, qf0, Z16, 0, 0, 0); \
    sa = __builtin_amdgcn_mfma_f32_32x32x16_f16(k1, qf1, sa, 0, 0, 0);         \
    const char* b0 = raw + (va0 | _bs);                                        \
    const char* b1 = raw + (va1 | _bs);                                        \
    const char* b2 = raw + (va2 | _bs);                                        \
    const char* b3 = raw + (va3 | _bs);                                        \
    uint2 r0, r1;                                                              \
    uint4v v00, v01, v10, v11;                                                 \
    r0 = *(const uint2*)(b0);        r1 = *(const uint2*)(b1);                 \
    v00 = (uint4v){r0.x, r0.y, r1.x, r1.y};                                    \
    r0 = *(const uint2*)(b2);        r1 = *(const uint2*)(b3);                 \
    v01 = (uint4v){r0.x, r0.y, r1.x, r1.y};                                    \
    r0 = *(const uint2*)(b0 + 2048); r1 = *(const uint2*)(b1 + 2048);          \
    v10 = (uint4v){r0.x, r0.y, r1.x, r1.y};                                    \
    r0 = *(const uint2*)(b2 + 2048); r1 = *(const uint2*)(b3 + 2048);          \
    v11 = (uint4v){r0.x, r0.y, r1.x, r1.y};                                    \
    float p[16];                                                               \
    _Pragma("unroll")                                                          \
    for (int r = 0; r < 16; ++r) p[r] = __builtin_amdgcn_exp2f(sa[r]);         \
    float s0 = 0.f, s1 = 0.f;                                                  \
    _Pragma("unroll")                                                          \
    for (int r = 0; r < 16; r += 2) { s0 += p[r]; s1 += p[r + 1]; }            \
    vsum += s0 + s1;                                                           \
    u32 pk[8];                                                                 \
    _Pragma("unroll")                                                          \
    for (int i = 0; i < 8; ++i) pk[i] = cvtpk_bf16(p[2 * i], p[2 * i + 1]);    \
    uint4v pa0u = {pk[0], pk[1], pk[2], pk[3]};                                \
    uint4v pa1u = {pk[4], pk[5], pk[6], pk[7]};                                \
    short8 pa0 = __builtin_bit_cast(short8, pa0u);                             \
    short8 pa1 = __builtin_bit_cast(short8, pa1u);                             \
    __builtin_amdgcn_s_setprio(1);                                             \
    acc0 = __builtin_amdgcn_mfma_f32_32x32x16_bf16(pa0, __builtin_bit_cast(short8, v00), acc0, 0, 0, 0); \
    acc0 = __builtin_amdgcn_mfma_f32_32x32x16_bf16(pa1, __builtin_bit_cast(short8, v01), acc0, 0, 0, 0); \
    acc1 = __builtin_amdgcn_mfma_f32_32x32x16_bf16(pa0, __builtin_bit_cast(short8, v10), acc1, 0, 0, 0); \
    acc1 = __builtin_amdgcn_mfma_f32_32x32x16_bf16(pa1, __builtin_bit_cast(short8, v11), acc1, 0, 0, 0); \
    __builtin_amdgcn_s_setprio(0);                                             \
  }

__global__ __launch_bounds__(512, 2)
void k_attn(const u16* __restrict__ q, const u16* __restrict__ kmat,
            const u16* __restrict__ hbf, const float* __restrict__ xin,
            const float* __restrict__ gam, float* __restrict__ out)
{
  __shared__ __align__(16) char raw[73984];
  // V: [0, 65536) = 4 bufs x [256 ch][32 keys u16] (16KB each)
  // K: [65536, 73728) = 4 bufs x [32 rows][32 ch u16] (2KB each)
  // invL: [73728, 73984)
  float* invL = (float*)(raw + 73728);

  int bid = blockIdx.x, t = threadIdx.x;
  int xcd = bid & 7;
  int b = xcd >> 1;                          // batch pinned to 2 XCDs
  int mg = ((xcd & 1) << 5) | (bid >> 3);    // 0..63
  int m0 = mg << 6;
  int w = t >> 6, l = t & 63, l31 = l & 31, hi = l >> 5;
  int msub = w & 1, ch = w >> 1;
  int mb = m0 + msub * 32;
  int c0 = ch * 64;                          // wave's 64-channel V slice

  const u16* qb = q + (size_t)b * 4096 * 32;
  const u16* kb = kmat + (size_t)b * 4096 * 32;
  const u16* hb = hbf + (size_t)b * 256 * 4096;

  half8 qf0 = *(const half8*)&qb[(mb + l31) * 32 + hi * 8];
  half8 qf1 = *(const half8*)&qb[(mb + l31) * 32 + 16 + hi * 8];

  f32x16 Z16 = {0,0,0,0,0,0,0,0,0,0,0,0,0,0,0,0};
  f32x16 acc0 = Z16, acc1 = Z16;
  float vsum = 0.f;

  // ---- per-lane staging source pointers (tile 0) ----
  int u0 = w * 128 + l, u1 = u0 + 64;
  int sc0 = u0 >> 2, sc1 = u1 >> 2;
  int qg0 = (l & 3) ^ ((sc0 >> 1) & 3);
  int qg1 = (l & 3) ^ ((sc1 >> 1) & 3);
  const char* vp0 = (const char*)hb + (size_t)sc0 * 8192 + qg0 * 16;
  const char* vp1 = (const char*)hb + (size_t)sc1 * 8192 + qg1 * 16;
  int kg = w * 16 + (l & 15);
  int krow = kg >> 2;
  int kz = (krow & 3) ^ ((krow >> 2) & 3);
  int kqg = (kg & 3) ^ kz;
  const char* kp = (const char*)kb + krow * 64 + kqg * 16;

  // ---- LDS read address regs ----
  int vrow = c0 + l31;
  int sv = ((vrow >> 1) & 3) << 1;
  int va0 = vrow * 64 + (((0 + hi) ^ sv) * 8);
  int va1 = vrow * 64 + (((2 + hi) ^ sv) * 8);
  int va2 = vrow * 64 + (((4 + hi) ^ sv) * 8);
  int va3 = vrow * 64 + (((6 + hi) ^ sv) * 8);
  int rz = (l31 & 3) ^ ((l31 >> 2) & 3);
  int ka0 = 65536 + l31 * 64 + (((0 + hi) ^ rz) * 16);
  int ka1 = 65536 + l31 * 64 + (((2 + hi) ^ rz) * 16);

  // ---- LDS dest bases (wave-uniform; HW adds lane*16) ----
  int vdst0 = w * 2048, vdst1 = w * 2048 + 1024;
  int kdst = 65536 + w * 256;

  // ---- prologue: stage tiles 0, 1 ----
  gll16(vp0, raw + vdst0);
  gll16(vp1, raw + vdst1);
  if (l < 16) gll16(kp, raw + kdst);
  gll16(vp0 + 64, raw + 16384 + vdst0);
  gll16(vp1 + 64, raw + 16384 + vdst1);
  if (l < 16) gll16(kp + 2048, raw + 65536 + 2048 + w * 256);   // buf1 (FIXED)
  vp0 += 128; vp1 += 128; kp += 4096;        // now at tile 2
  asm volatile("s_waitcnt vmcnt(3)" ::: "memory");
  __builtin_amdgcn_sched_barrier(0);
  __builtin_amdgcn_s_barrier();

  // ---- main loop: steps 0..125 stage tile it+2 ----
  for (int it = 0; it < 126; ++it) {
    int sbuf = (it + 2) & 3;
    gll16(vp0, raw + (sbuf << 14) + vdst0);
    gll16(vp1, raw + (sbuf << 14) + vdst1);
    if (l < 16) gll16(kp, raw + 65536 + (sbuf << 11) + w * 256);
    vp0 += 64; vp1 += 64; kp += 2048;
    COMPUTE(it & 3);
    asm volatile("s_waitcnt vmcnt(3)" ::: "memory");
    __builtin_amdgcn_sched_barrier(0);
    __builtin_amdgcn_s_barrier();
  }
  // step 126 (buf 2): nothing left to stage; tile 127 must land
  COMPUTE(2);
  asm volatile("s_waitcnt vmcnt(0)" ::: "memory");
  __builtin_amdgcn_sched_barrier(0);
  __builtin_amdgcn_s_barrier();
  // step 127 (buf 3)
  COMPUTE(3);

  // ---- epilogue: normalize + write (row sums identical across ch waves) ----
  float vt = vsum + __shfl_xor(vsum, 32);
  if (w < 2 && l < 32) invL[msub * 32 + l31] = 1.0f / vt;
  __syncthreads();
  {
    float gamma = gam[0];
    const float* xb = xin + (size_t)b * 256 * 4096;
    float* ob = out + (size_t)b * 256 * 4096;
    f32x16 acc[2] = {acc0, acc1};
#pragma unroll
    for (int g = 0; g < 4; ++g) {
      float4 inv4 = *(const float4*)&invL[msub * 32 + 8 * g + 4 * hi];
#pragma unroll
      for (int ct = 0; ct < 2; ++ct) {
        int c = c0 + ct * 32 + l31;
        size_t base = (size_t)c * 4096 + mb + 8 * g + 4 * hi;
        float4 xv = *(const float4*)&xb[base];
        float4 ov;
        ov.x = gamma * acc[ct][4 * g + 0] * inv4.x + xv.x;
        ov.y = gamma * acc[ct][4 * g + 1] * inv4.y + xv.y;
        ov.z = gamma * acc[ct][4 * g + 2] * inv4.z + xv.z;
        ov.w = gamma * acc[ct][4 * g + 3] * inv4.w + xv.w;
        *(float4*)&ob[base] = ov;
      }
    }
  }
}

// ---------------------------------------------------------------------------
extern "C" void kernel_launch(void* const* d_in, const int* in_sizes, int n_in,
                              void* d_out, int out_size, void* d_ws, size_t ws_size,
                              hipStream_t stream)
{
  const float* x   = (const float*)d_in[0];
  const float* Wf  = (const float*)d_in[1];
  const float* bfp = (const float*)d_in[2];
  const float* Wg  = (const float*)d_in[3];
  const float* bgp = (const float*)d_in[4];
  const float* Wh  = (const float*)d_in[5];
  const float* bhp = (const float*)d_in[6];
  const float* gam = (const float*)d_in[7];
  float* out = (float*)d_out;

  char* ws = (char*)d_ws;
  u16*   xT   = (u16*)(ws);                  // 8,388,608 B  f16 [4][4096][256]
  u16*   Wall = (u16*)(ws + 8388608);        //   163,840 B  f16 [320][256]
  float* ball = (float*)(ws + 8552448);      //     2,048 B  f32 [320]
  u16*   q    = (u16*)(ws + 8554496);        // 2,097,152 B  f16 [4][4096][32]  (g, *log2e)
  u16*   km   = (u16*)(ws + 10651648);       // 2,097,152 B  f16 [4][4096][32]  (f)
  u16*   hbf  = (u16*)(ws + 12748800);       // 8,388,608 B  bf16 [4][256][4096] (h)

  k_prep<<<dim3(1104), dim3(256), 0, stream>>>(x, Wf, bfp, Wg, bgp, Wh, bhp, xT, Wall, ball);
  k_proj<<<dim3(1280), dim3(256), 0, stream>>>(xT, Wall, ball, q, km, hbf);
  k_attn<<<dim3(256),  dim3(512), 0, stream>>>(q, km, hbf, x, gam, out);
}

// Round 8
// 147.245 us; speedup vs baseline: 1.1522x; 1.1522x over previous
//
#include <hip/hip_runtime.h>
#include <hip/hip_bf16.h>
#include <hip/hip_fp16.h>

typedef __attribute__((ext_vector_type(8))) short short8;     // bf16x8 frag
typedef __attribute__((ext_vector_type(8))) _Float16 half8;   // f16x8 frag
typedef __attribute__((ext_vector_type(4))) float f32x4;
typedef __attribute__((ext_vector_type(16))) float f32x16;
typedef __attribute__((ext_vector_type(4))) unsigned int uint4v;
typedef unsigned short u16;
typedef unsigned int u32;

#define LOG2E 1.44269504088896f

typedef const void __attribute__((address_space(1))) gvoid;
typedef void __attribute__((address_space(3))) lvoid;

__device__ __forceinline__ void gll16(const void* g, void* l) {
  __builtin_amdgcn_global_load_lds((gvoid*)g, (lvoid*)l, 16, 0, 0);
}

__device__ __forceinline__ u16 f2bf(float f) {
  u32 u = __builtin_bit_cast(u32, f);
  u += 0x7fffu + ((u >> 16) & 1u);
  return (u16)(u >> 16);
}
__device__ __forceinline__ u16 f2h(float f) {
  _Float16 h = (_Float16)f;
  return __builtin_bit_cast(u16, h);
}
__device__ __forceinline__ u32 cvtpk_bf16(float lo, float hi) {
  u32 r;
  asm("v_cvt_pk_bf16_f32 %0, %1, %2" : "=v"(r) : "v"(lo), "v"(hi));
  return r;
}

// ---------------------------------------------------------------------------
// K0: prep (unchanged).
// ---------------------------------------------------------------------------
__global__ void k_prep(const float* __restrict__ x,
                       const float* __restrict__ Wf, const float* __restrict__ bfp,
                       const float* __restrict__ Wg, const float* __restrict__ bgp,
                       const float* __restrict__ Wh, const float* __restrict__ bhp,
                       u16* __restrict__ xT, u16* __restrict__ Wall,
                       float* __restrict__ ball)
{
  int bid = blockIdx.x, t = threadIdx.x;
  if (bid < 1024) {
    __shared__ u16 tile[64][68];
    int b = bid >> 8, c0 = ((bid >> 6) & 3) << 6, n0 = (bid & 63) << 6;
#pragma unroll
    for (int r = 0; r < 4; ++r) {
      int cl = (t >> 4) + r * 16, nl = (t & 15) * 4;
      const float4 v = *(const float4*)&x[(size_t)(b * 256 + c0 + cl) * 4096 + n0 + nl];
      tile[cl][nl + 0] = f2h(v.x); tile[cl][nl + 1] = f2h(v.y);
      tile[cl][nl + 2] = f2h(v.z); tile[cl][nl + 3] = f2h(v.w);
    }
    __syncthreads();
#pragma unroll
    for (int r = 0; r < 4; ++r) {
      int nl = (t >> 4) + r * 16, cl = (t & 15) * 4;
      ushort4 o;
      o.x = tile[cl + 0][nl]; o.y = tile[cl + 1][nl];
      o.z = tile[cl + 2][nl]; o.w = tile[cl + 3][nl];
      *(ushort4*)&xT[(size_t)(b * 4096 + n0 + nl) * 256 + c0 + cl] = o;
    }
  } else {
    int wb = bid - 1024;                 // 0..79
    int e = wb * 1024 + t * 4;           // element in W_all (320*256)
    int r = e >> 8;
    const float* src = (r < 32) ? (Wf + e)
                     : (r < 64) ? (Wg + e - 32 * 256)
                                : (Wh + e - 64 * 256);
    float4 v = *(const float4*)src;
    float sc = (r >= 32 && r < 64) ? LOG2E : 1.0f;   // pre-scale Q path
    ushort4 o;
    o.x = f2h(v.x * sc); o.y = f2h(v.y * sc);
    o.z = f2h(v.z * sc); o.w = f2h(v.w * sc);
    *(ushort4*)&Wall[e] = o;
    if (wb == 0 && t < 80) {
#pragma unroll
      for (int i = 0; i < 4; ++i) {
        int idx = t * 4 + i;
        ball[idx] = (idx < 32) ? bfp[idx]
                  : (idx < 64) ? bgp[idx - 32] * LOG2E
                               : bhp[idx - 64];
      }
    }
  }
}

// ---------------------------------------------------------------------------
// K1: projections via f16 MFMA (unchanged).
// ---------------------------------------------------------------------------
__global__ __launch_bounds__(256, 4)
void k_proj(const u16* __restrict__ xT, const u16* __restrict__ Wall,
            const float* __restrict__ ball,
            u16* __restrict__ q, u16* __restrict__ kmat, u16* __restrict__ hbf)
{
  int bid = blockIdx.x, t = threadIdx.x;
  int w = t >> 6, l = t & 63, lg = l >> 4, li = l & 15;
  f32x4 Z = {0.f, 0.f, 0.f, 0.f};
  if (bid < 256) {        // ---- FG ----
    int b = bid >> 6, n0 = (bid & 63) << 6;
    int rbase = w * 16;
    half8 aw[8];
#pragma unroll
    for (int kk = 0; kk < 8; ++kk)
      aw[kk] = *(const half8*)&Wall[(rbase + li) * 256 + kk * 32 + lg * 8];
    float bias[4];
#pragma unroll
    for (int j = 0; j < 4; ++j) bias[j] = ball[rbase + 4 * lg + j];
#pragma unroll
    for (int nn = 0; nn < 4; ++nn) {
      int n = n0 + nn * 16 + li;
      f32x4 acc = Z;
#pragma unroll
      for (int kk = 0; kk < 8; ++kk) {
        half8 bx = *(const half8*)&xT[(size_t)(b * 4096 + n) * 256 + kk * 32 + lg * 8];
        acc = __builtin_amdgcn_mfma_f32_16x16x32_f16(aw[kk], bx, acc, 0, 0, 0);
      }
      ushort4 o;
      o.x = f2h(acc[0] + bias[0]); o.y = f2h(acc[1] + bias[1]);
      o.z = f2h(acc[2] + bias[2]); o.w = f2h(acc[3] + bias[3]);
      u16* dst = (rbase < 32)
               ? (kmat + (size_t)(b * 4096 + n) * 32 + rbase + 4 * lg)
               : (q    + (size_t)(b * 4096 + n) * 32 + (rbase - 32) + 4 * lg);
      *(ushort4*)dst = o;
    }
  } else {                // ---- H ----
    int hb = bid - 256;
    int b = hb >> 8, rt = (hb >> 6) & 3, n0 = (hb & 63) << 6;
    int r0 = 64 + rt * 64;
    int nbase = n0 + w * 16;
    half8 ax[8];
#pragma unroll
    for (int kk = 0; kk < 8; ++kk)
      ax[kk] = *(const half8*)&xT[(size_t)(b * 4096 + nbase + li) * 256 + kk * 32 + lg * 8];
#pragma unroll
    for (int rr = 0; rr < 4; ++rr) {
      int r = r0 + rr * 16 + li;
      f32x4 acc = Z;
#pragma unroll
      for (int kk = 0; kk < 8; ++kk) {
        half8 bw = *(const half8*)&Wall[r * 256 + kk * 32 + lg * 8];
        acc = __builtin_amdgcn_mfma_f32_16x16x32_f16(ax[kk], bw, acc, 0, 0, 0);
      }
      float bias = ball[r];
      ushort4 o;
      o.x = f2bf(acc[0] + bias); o.y = f2bf(acc[1] + bias);
      o.z = f2bf(acc[2] + bias); o.w = f2bf(acc[3] + bias);
      *(ushort4*)&hbf[(size_t)(b * 256 + r - 64) * 4096 + nbase + 4 * lg] = o;
    }
  }
}

// ---------------------------------------------------------------------------
// K2 v7: M=32/block, 4 waves ch(4), grid 512 (2 blocks/CU), counted-vmcnt
//  4-buf pipeline with prefetch distance 3.
//  Per step/wave: 5 gll16 (4 V + 1 K) for tile it+3 -> COMPUTE buf it&3 ->
//  s_waitcnt vmcnt(10) (tiles it+2,it+3 stay in flight) -> raw s_barrier.
//  LDS: V 4x16KB [0,64K), K 4x2KB [64K,72K), invL @73728. 73.9KB -> 2/CU.
//  Staging & read swizzles verbatim from passing R4/R6 kernels.
// ---------------------------------------------------------------------------
#define COMPUTE(BUFC)                                                          \
  {                                                                            \
    const int _bs = (BUFC) << 14;                                              \
    const int _bk = (BUFC) << 11;                                              \
    half8 k0 = *(const half8*)(raw + (ka0 | _bk));                             \
    half8 k1 = *(const half8*)(raw + (ka1 | _bk));                             \
    f32x16 sa = __builtin_amdgcn_mfma_f32_32x32x16_f16(k0, qf0, Z16, 0, 0, 0); \
    sa = __builtin_amdgcn_mfma_f32_32x32x16_f16(k1, qf1, sa, 0, 0, 0);         \
    const char* b0 = raw + (va0 | _bs);                                        \
    const char* b1 = raw + (va1 | _bs);                                        \
    const char* b2 = raw + (va2 | _bs);                                        \
    const char* b3 = raw + (va3 | _bs);                                        \
    uint2 r0, r1;                                                              \
    uint4v v00, v01, v10, v11;                                                 \
    r0 = *(const uint2*)(b0);        r1 = *(const uint2*)(b1);                 \
    v00 = (uint4v){r0.x, r0.y, r1.x, r1.y};                                    \
    r0 = *(const uint2*)(b2);        r1 = *(const uint2*)(b3);                 \
    v01 = (uint4v){r0.x, r0.y, r1.x, r1.y};                                    \
    r0 = *(const uint2*)(b0 + 2048); r1 = *(const uint2*)(b1 + 2048);          \
    v10 = (uint4v){r0.x, r0.y, r1.x, r1.y};                                    \
    r0 = *(const uint2*)(b2 + 2048); r1 = *(const uint2*)(b3 + 2048);          \
    v11 = (uint4v){r0.x, r0.y, r1.x, r1.y};                                    \
    float p[16];                                                               \
    _Pragma("unroll")                                                          \
    for (int r = 0; r < 16; ++r) p[r] = __builtin_amdgcn_exp2f(sa[r]);         \
    float s0 = 0.f, s1 = 0.f;                                                  \
    _Pragma("unroll")                                                          \
    for (int r = 0; r < 16; r += 2) { s0 += p[r]; s1 += p[r + 1]; }            \
    vsum += s0 + s1;                                                           \
    u32 pk[8];                                                                 \
    _Pragma("unroll")                                                          \
    for (int i = 0; i < 8; ++i) pk[i] = cvtpk_bf16(p[2 * i], p[2 * i + 1]);    \
    uint4v pa0u = {pk[0], pk[1], pk[2], pk[3]};                                \
    uint4v pa1u = {pk[4], pk[5], pk[6], pk[7]};                                \
    short8 pa0 = __builtin_bit_cast(short8, pa0u);                             \
    short8 pa1 = __builtin_bit_cast(short8, pa1u);                             \
    __builtin_amdgcn_s_setprio(1);                                             \
    acc0 = __builtin_amdgcn_mfma_f32_32x32x16_bf16(pa0, __builtin_bit_cast(short8, v00), acc0, 0, 0, 0); \
    acc0 = __builtin_amdgcn_mfma_f32_32x32x16_bf16(pa1, __builtin_bit_cast(short8, v01), acc0, 0, 0, 0); \
    acc1 = __builtin_amdgcn_mfma_f32_32x32x16_bf16(pa0, __builtin_bit_cast(short8, v10), acc1, 0, 0, 0); \
    acc1 = __builtin_amdgcn_mfma_f32_32x32x16_bf16(pa1, __builtin_bit_cast(short8, v11), acc1, 0, 0, 0); \
    __builtin_amdgcn_s_setprio(0);                                             \
  }

__global__ __launch_bounds__(256, 2)
void k_attn(const u16* __restrict__ q, const u16* __restrict__ kmat,
            const u16* __restrict__ hbf, const float* __restrict__ xin,
            const float* __restrict__ gam, float* __restrict__ out)
{
  __shared__ __align__(16) char raw[73856];
  // V: [0, 65536) = 4 bufs x [256 ch][32 keys u16] (16KB each)
  // K: [65536, 73728) = 4 bufs x [32 rows][32 ch u16] (2KB each)
  // invL: [73728, 73856)
  float* invL = (float*)(raw + 73728);

  int bid = blockIdx.x, t = threadIdx.x;
  int xcd = bid & 7;
  int b = xcd >> 1;                          // batch pinned to 2 XCDs
  int mg = ((xcd & 1) << 6) | (bid >> 3);    // 0..127
  int m0 = mg << 5;
  int w = t >> 6, l = t & 63, l31 = l & 31, hi = l >> 5;
  int c0 = w * 64;                           // wave's 64-channel V slice

  const u16* qb = q + (size_t)b * 4096 * 32;
  const u16* kb = kmat + (size_t)b * 4096 * 32;
  const u16* hb = hbf + (size_t)b * 256 * 4096;

  half8 qf0 = *(const half8*)&qb[(m0 + l31) * 32 + hi * 8];
  half8 qf1 = *(const half8*)&qb[(m0 + l31) * 32 + 16 + hi * 8];

  f32x16 Z16 = {0,0,0,0,0,0,0,0,0,0,0,0,0,0,0,0};
  f32x16 acc0 = Z16, acc1 = Z16;
  float vsum = 0.f;

  // ---- V staging source (per-lane):
  //  granule u_i = i*256 + w*64 + l ; sc_i = i*64 + w*16 + (l>>2);
  //  qg = (l&3) ^ ((l>>3)&3)   (independent of i and w)
  int scb = w * 16 + (l >> 2);
  int qg = (l & 3) ^ ((l >> 3) & 3);
  const char* vp = (const char*)hb + (size_t)scb * 8192 + qg * 16;
  // ---- K staging source (lanes l<32): granule g = w*32 + l ;
  //  krow = w*8 + (l>>2); z = (krow&3)^((krow>>2)&3); qg = (l&3)^z
  int krow = w * 8 + ((l & 31) >> 2);
  int kz = (krow & 3) ^ ((krow >> 2) & 3);
  int kqg = (l & 3) ^ kz;
  const char* kp = (const char*)kb + krow * 64 + kqg * 16;

  // ---- LDS read address regs (swizzles verbatim R4/R6) ----
  int vrow = c0 + l31;
  int sv = ((vrow >> 1) & 3) << 1;
  int va0 = vrow * 64 + (((0 + hi) ^ sv) * 8);
  int va1 = vrow * 64 + (((2 + hi) ^ sv) * 8);
  int va2 = vrow * 64 + (((4 + hi) ^ sv) * 8);
  int va3 = vrow * 64 + (((6 + hi) ^ sv) * 8);
  int rz = (l31 & 3) ^ ((l31 >> 2) & 3);
  int ka0 = 65536 + l31 * 64 + (((0 + hi) ^ rz) * 16);
  int ka1 = 65536 + l31 * 64 + (((2 + hi) ^ rz) * 16);

  // ---- LDS dest bases (wave-uniform; HW adds lane*16) ----
  int vd = w * 1024;              // + buf*16384 + i*4096
  int kd = 65536 + w * 512;       // + buf*2048

  // ---- prologue: stage tiles 0, 1, 2 into bufs 0, 1, 2 ----
#pragma unroll
  for (int tp = 0; tp < 3; ++tp) {
    gll16(vp + tp * 64,           raw + tp * 16384 + vd);
    gll16(vp + tp * 64 +  524288, raw + tp * 16384 + vd + 4096);
    gll16(vp + tp * 64 + 1048576, raw + tp * 16384 + vd + 8192);
    gll16(vp + tp * 64 + 1572864, raw + tp * 16384 + vd + 12288);
    if (l < 32) gll16(kp + tp * 2048, raw + kd + tp * 2048);
  }
  vp += 192; kp += 6144;          // now at tile 3
  asm volatile("s_waitcnt vmcnt(10)" ::: "memory");
  __builtin_amdgcn_sched_barrier(0);
  __builtin_amdgcn_s_barrier();

  // ---- main loop: steps 0..124 stage tile it+3 ----
  for (int it = 0; it < 125; ++it) {
    int sbuf = (it + 3) & 3;
    gll16(vp,           raw + (sbuf << 14) + vd);
    gll16(vp +  524288, raw + (sbuf << 14) + vd + 4096);
    gll16(vp + 1048576, raw + (sbuf << 14) + vd + 8192);
    gll16(vp + 1572864, raw + (sbuf << 14) + vd + 12288);
    if (l < 32) gll16(kp, raw + kd + (sbuf << 11));
    vp += 64; kp += 2048;
    COMPUTE(it & 3);
    asm volatile("s_waitcnt vmcnt(10)" ::: "memory");
    __builtin_amdgcn_sched_barrier(0);
    __builtin_amdgcn_s_barrier();
  }
  // step 125 (buf 1): tile 126 must land
  COMPUTE(1);
  asm volatile("s_waitcnt vmcnt(5)" ::: "memory");
  __builtin_amdgcn_sched_barrier(0);
  __builtin_amdgcn_s_barrier();
  // step 126 (buf 2): tile 127 must land
  COMPUTE(2);
  asm volatile("s_waitcnt vmcnt(0)" ::: "memory");
  __builtin_amdgcn_sched_barrier(0);
  __builtin_amdgcn_s_barrier();
  // step 127 (buf 3)
  COMPUTE(3);

  // ---- epilogue: normalize + write (R4-style, no merge) ----
  float vt = vsum + __shfl_xor(vsum, 32);
  if (w == 0 && l < 32) invL[l31] = 1.0f / vt;
  __syncthreads();
  {
    float gamma = gam[0];
    const float* xb = xin + (size_t)b * 256 * 4096;
    float* ob = out + (size_t)b * 256 * 4096;
    f32x16 acc[2] = {acc0, acc1};
#pragma unroll
    for (int g = 0; g < 4; ++g) {
      float4 inv4 = *(const float4*)&invL[8 * g + 4 * hi];
#pragma unroll
      for (int ct = 0; ct < 2; ++ct) {
        int c = c0 + ct * 32 + l31;
        size_t base = (size_t)c * 4096 + m0 + 8 * g + 4 * hi;
        float4 xv = *(const float4*)&xb[base];
        float4 ov;
        ov.x = gamma * acc[ct][4 * g + 0] * inv4.x + xv.x;
        ov.y = gamma * acc[ct][4 * g + 1] * inv4.y + xv.y;
        ov.z = gamma * acc[ct][4 * g + 2] * inv4.z + xv.z;
        ov.w = gamma * acc[ct][4 * g + 3] * inv4.w + xv.w;
        *(float4*)&ob[base] = ov;
      }
    }
  }
}

// ---------------------------------------------------------------------------
extern "C" void kernel_launch(void* const* d_in, const int* in_sizes, int n_in,
                              void* d_out, int out_size, void* d_ws, size_t ws_size,
                              hipStream_t stream)
{
  const float* x   = (const float*)d_in[0];
  const float* Wf  = (const float*)d_in[1];
  const float* bfp = (const float*)d_in[2];
  const float* Wg  = (const float*)d_in[3];
  const float* bgp = (const float*)d_in[4];
  const float* Wh  = (const float*)d_in[5];
  const float* bhp = (const float*)d_in[6];
  const float* gam = (const float*)d_in[7];
  float* out = (float*)d_out;

  char* ws = (char*)d_ws;
  u16*   xT   = (u16*)(ws);                  // 8,388,608 B  f16 [4][4096][256]
  u16*   Wall = (u16*)(ws + 8388608);        //   163,840 B  f16 [320][256]
  float* ball = (float*)(ws + 8552448);      //     2,048 B  f32 [320]
  u16*   q    = (u16*)(ws + 8554496);        // 2,097,152 B  f16 [4][4096][32]  (g, *log2e)
  u16*   km   = (u16*)(ws + 10651648);       // 2,097,152 B  f16 [4][4096][32]  (f)
  u16*   hbf  = (u16*)(ws + 12748800);       // 8,388,608 B  bf16 [4][256][4096] (h)

  k_prep<<<dim3(1104), dim3(256), 0, stream>>>(x, Wf, bfp, Wg, bgp, Wh, bhp, xT, Wall, ball);
  k_proj<<<dim3(1280), dim3(256), 0, stream>>>(xT, Wall, ball, q, km, hbf);
  k_attn<<<dim3(512),  dim3(256), 0, stream>>>(q, km, hbf, x, gam, out);
}

// Round 9
// 127.059 us; speedup vs baseline: 1.3352x; 1.1589x over previous
//
#include <hip/hip_runtime.h>
#include <hip/hip_bf16.h>
#include <hip/hip_fp16.h>

typedef __attribute__((ext_vector_type(8))) short short8;     // bf16x8 frag
typedef __attribute__((ext_vector_type(8))) _Float16 half8;   // f16x8 frag
typedef __attribute__((ext_vector_type(4))) float f32x4;
typedef __attribute__((ext_vector_type(16))) float f32x16;
typedef __attribute__((ext_vector_type(4))) unsigned int uint4v;
typedef unsigned short u16;
typedef unsigned int u32;

#define LOG2E 1.44269504088896f

typedef const void __attribute__((address_space(1))) gvoid;
typedef void __attribute__((address_space(3))) lvoid;

__device__ __forceinline__ void gll16(const void* g, void* l) {
  __builtin_amdgcn_global_load_lds((gvoid*)g, (lvoid*)l, 16, 0, 0);
}

__device__ __forceinline__ u16 f2bf(float f) {
  u32 u = __builtin_bit_cast(u32, f);
  u += 0x7fffu + ((u >> 16) & 1u);
  return (u16)(u >> 16);
}
__device__ __forceinline__ u16 f2h(float f) {
  _Float16 h = (_Float16)f;
  return __builtin_bit_cast(u16, h);
}
__device__ __forceinline__ u32 cvtpk_bf16(float lo, float hi) {
  u32 r;
  asm("v_cvt_pk_bf16_f32 %0, %1, %2" : "=v"(r) : "v"(lo), "v"(hi));
  return r;
}

// ---------------------------------------------------------------------------
// K0: prep (unchanged).
// ---------------------------------------------------------------------------
__global__ void k_prep(const float* __restrict__ x,
                       const float* __restrict__ Wf, const float* __restrict__ bfp,
                       const float* __restrict__ Wg, const float* __restrict__ bgp,
                       const float* __restrict__ Wh, const float* __restrict__ bhp,
                       u16* __restrict__ xT, u16* __restrict__ Wall,
                       float* __restrict__ ball)
{
  int bid = blockIdx.x, t = threadIdx.x;
  if (bid < 1024) {
    __shared__ u16 tile[64][68];
    int b = bid >> 8, c0 = ((bid >> 6) & 3) << 6, n0 = (bid & 63) << 6;
#pragma unroll
    for (int r = 0; r < 4; ++r) {
      int cl = (t >> 4) + r * 16, nl = (t & 15) * 4;
      const float4 v = *(const float4*)&x[(size_t)(b * 256 + c0 + cl) * 4096 + n0 + nl];
      tile[cl][nl + 0] = f2h(v.x); tile[cl][nl + 1] = f2h(v.y);
      tile[cl][nl + 2] = f2h(v.z); tile[cl][nl + 3] = f2h(v.w);
    }
    __syncthreads();
#pragma unroll
    for (int r = 0; r < 4; ++r) {
      int nl = (t >> 4) + r * 16, cl = (t & 15) * 4;
      ushort4 o;
      o.x = tile[cl + 0][nl]; o.y = tile[cl + 1][nl];
      o.z = tile[cl + 2][nl]; o.w = tile[cl + 3][nl];
      *(ushort4*)&xT[(size_t)(b * 4096 + n0 + nl) * 256 + c0 + cl] = o;
    }
  } else {
    int wb = bid - 1024;                 // 0..79
    int e = wb * 1024 + t * 4;           // element in W_all (320*256)
    int r = e >> 8;
    const float* src = (r < 32) ? (Wf + e)
                     : (r < 64) ? (Wg + e - 32 * 256)
                                : (Wh + e - 64 * 256);
    float4 v = *(const float4*)src;
    float sc = (r >= 32 && r < 64) ? LOG2E : 1.0f;   // pre-scale Q path
    ushort4 o;
    o.x = f2h(v.x * sc); o.y = f2h(v.y * sc);
    o.z = f2h(v.z * sc); o.w = f2h(v.w * sc);
    *(ushort4*)&Wall[e] = o;
    if (wb == 0 && t < 80) {
#pragma unroll
      for (int i = 0; i < 4; ++i) {
        int idx = t * 4 + i;
        ball[idx] = (idx < 32) ? bfp[idx]
                  : (idx < 64) ? bgp[idx - 32] * LOG2E
                               : bhp[idx - 64];
      }
    }
  }
}

// ---------------------------------------------------------------------------
// K1: projections via f16 MFMA (unchanged).
// ---------------------------------------------------------------------------
__global__ __launch_bounds__(256, 4)
void k_proj(const u16* __restrict__ xT, const u16* __restrict__ Wall,
            const float* __restrict__ ball,
            u16* __restrict__ q, u16* __restrict__ kmat, u16* __restrict__ hbf)
{
  int bid = blockIdx.x, t = threadIdx.x;
  int w = t >> 6, l = t & 63, lg = l >> 4, li = l & 15;
  f32x4 Z = {0.f, 0.f, 0.f, 0.f};
  if (bid < 256) {        // ---- FG ----
    int b = bid >> 6, n0 = (bid & 63) << 6;
    int rbase = w * 16;
    half8 aw[8];
#pragma unroll
    for (int kk = 0; kk < 8; ++kk)
      aw[kk] = *(const half8*)&Wall[(rbase + li) * 256 + kk * 32 + lg * 8];
    float bias[4];
#pragma unroll
    for (int j = 0; j < 4; ++j) bias[j] = ball[rbase + 4 * lg + j];
#pragma unroll
    for (int nn = 0; nn < 4; ++nn) {
      int n = n0 + nn * 16 + li;
      f32x4 acc = Z;
#pragma unroll
      for (int kk = 0; kk < 8; ++kk) {
        half8 bx = *(const half8*)&xT[(size_t)(b * 4096 + n) * 256 + kk * 32 + lg * 8];
        acc = __builtin_amdgcn_mfma_f32_16x16x32_f16(aw[kk], bx, acc, 0, 0, 0);
      }
      ushort4 o;
      o.x = f2h(acc[0] + bias[0]); o.y = f2h(acc[1] + bias[1]);
      o.z = f2h(acc[2] + bias[2]); o.w = f2h(acc[3] + bias[3]);
      u16* dst = (rbase < 32)
               ? (kmat + (size_t)(b * 4096 + n) * 32 + rbase + 4 * lg)
               : (q    + (size_t)(b * 4096 + n) * 32 + (rbase - 32) + 4 * lg);
      *(ushort4*)dst = o;
    }
  } else {                // ---- H ----
    int hb = bid - 256;
    int b = hb >> 8, rt = (hb >> 6) & 3, n0 = (hb & 63) << 6;
    int r0 = 64 + rt * 64;
    int nbase = n0 + w * 16;
    half8 ax[8];
#pragma unroll
    for (int kk = 0; kk < 8; ++kk)
      ax[kk] = *(const half8*)&xT[(size_t)(b * 4096 + nbase + li) * 256 + kk * 32 + lg * 8];
#pragma unroll
    for (int rr = 0; rr < 4; ++rr) {
      int r = r0 + rr * 16 + li;
      f32x4 acc = Z;
#pragma unroll
      for (int kk = 0; kk < 8; ++kk) {
        half8 bw = *(const half8*)&Wall[r * 256 + kk * 32 + lg * 8];
        acc = __builtin_amdgcn_mfma_f32_16x16x32_f16(ax[kk], bw, acc, 0, 0, 0);
      }
      float bias = ball[r];
      ushort4 o;
      o.x = f2bf(acc[0] + bias); o.y = f2bf(acc[1] + bias);
      o.z = f2bf(acc[2] + bias); o.w = f2bf(acc[3] + bias);
      *(ushort4*)&hbf[(size_t)(b * 256 + r - 64) * 4096 + nbase + 4 * lg] = o;
    }
  }
}

// ---------------------------------------------------------------------------
// K2 v8: barrier-FREE wave-private pipeline.
//  M=32/block, grid 512 (2 blocks/CU), 4 waves = ch(4).
//  Each wave: private V region (4 bufs x 4KB), stages its own 64ch x 32key
//  slice (4 gll16, distance 3); K direct global->regs (2 loads, distance 1);
//  end-of-body s_waitcnt vmcnt(12) — exact count, no s_barrier anywhere.
//  Epilogue: per-wave shfl-broadcast of 1/rowsum (no LDS, no syncthreads).
// ---------------------------------------------------------------------------
#define STAGEV(BUFS)                                                           \
  {                                                                            \
    int _d = wbase + ((BUFS) << 12);                                           \
    gll16(vp,          raw + _d);                                              \
    gll16(vp + 131072, raw + _d + 1024);                                       \
    gll16(vp + 262144, raw + _d + 2048);                                       \
    gll16(vp + 393216, raw + _d + 3072);                                       \
    vp += 64;                                                                  \
  }

#define COMPUTE(BUFC, KC0, KC1)                                                \
  {                                                                            \
    f32x16 sa = __builtin_amdgcn_mfma_f32_32x32x16_f16(KC0, qf0, Z16, 0, 0, 0);\
    sa = __builtin_amdgcn_mfma_f32_32x32x16_f16(KC1, qf1, sa, 0, 0, 0);        \
    const char* bb = raw + wbase + ((BUFC) << 12);                             \
    uint2 r0, r1;                                                              \
    uint4v v00, v01, v10, v11;                                                 \
    r0 = *(const uint2*)(bb + va0);        r1 = *(const uint2*)(bb + va1);     \
    v00 = (uint4v){r0.x, r0.y, r1.x, r1.y};                                    \
    r0 = *(const uint2*)(bb + va2);        r1 = *(const uint2*)(bb + va3);     \
    v01 = (uint4v){r0.x, r0.y, r1.x, r1.y};                                    \
    r0 = *(const uint2*)(bb + va0 + 2048); r1 = *(const uint2*)(bb + va1 + 2048);\
    v10 = (uint4v){r0.x, r0.y, r1.x, r1.y};                                    \
    r0 = *(const uint2*)(bb + va2 + 2048); r1 = *(const uint2*)(bb + va3 + 2048);\
    v11 = (uint4v){r0.x, r0.y, r1.x, r1.y};                                    \
    float p[16];                                                               \
    _Pragma("unroll")                                                          \
    for (int r = 0; r < 16; ++r) p[r] = __builtin_amdgcn_exp2f(sa[r]);         \
    float s0 = 0.f, s1 = 0.f;                                                  \
    _Pragma("unroll")                                                          \
    for (int r = 0; r < 16; r += 2) { s0 += p[r]; s1 += p[r + 1]; }            \
    vsum += s0 + s1;                                                           \
    u32 pk[8];                                                                 \
    _Pragma("unroll")                                                          \
    for (int i = 0; i < 8; ++i) pk[i] = cvtpk_bf16(p[2 * i], p[2 * i + 1]);    \
    uint4v pa0u = {pk[0], pk[1], pk[2], pk[3]};                                \
    uint4v pa1u = {pk[4], pk[5], pk[6], pk[7]};                                \
    short8 pa0 = __builtin_bit_cast(short8, pa0u);                             \
    short8 pa1 = __builtin_bit_cast(short8, pa1u);                             \
    __builtin_amdgcn_s_setprio(1);                                             \
    acc0 = __builtin_amdgcn_mfma_f32_32x32x16_bf16(pa0, __builtin_bit_cast(short8, v00), acc0, 0, 0, 0); \
    acc0 = __builtin_amdgcn_mfma_f32_32x32x16_bf16(pa1, __builtin_bit_cast(short8, v01), acc0, 0, 0, 0); \
    acc1 = __builtin_amdgcn_mfma_f32_32x32x16_bf16(pa0, __builtin_bit_cast(short8, v10), acc1, 0, 0, 0); \
    acc1 = __builtin_amdgcn_mfma_f32_32x32x16_bf16(pa1, __builtin_bit_cast(short8, v11), acc1, 0, 0, 0); \
    __builtin_amdgcn_s_setprio(0);                                             \
  }

#define VWAIT(N)                                                               \
  asm volatile("s_waitcnt vmcnt(" #N ")" ::: "memory");                        \
  __builtin_amdgcn_sched_barrier(0);

__global__ __launch_bounds__(256, 2)
void k_attn(const u16* __restrict__ q, const u16* __restrict__ kmat,
            const u16* __restrict__ hbf, const float* __restrict__ xin,
            const float* __restrict__ gam, float* __restrict__ out)
{
  __shared__ __align__(16) char raw[65536];   // [wave4][buf4][4KB]

  int bid = blockIdx.x, t = threadIdx.x;
  int xcd = bid & 7;
  int b = xcd >> 1;                          // batch pinned to 2 XCDs
  int mg = ((xcd & 1) << 6) | (bid >> 3);    // 0..127
  int m0 = mg << 5;
  int w = t >> 6, l = t & 63, l31 = l & 31, hi = l >> 5;
  int c0 = w * 64;                           // wave's private 64-channel slice
  int wbase = w << 14;                       // private LDS region (16KB)

  const u16* qb = q + (size_t)b * 4096 * 32;
  const u16* kb = kmat + (size_t)b * 4096 * 32;
  const u16* hb = hbf + (size_t)b * 256 * 4096;

  half8 qf0 = *(const half8*)&qb[(m0 + l31) * 32 + hi * 8];
  half8 qf1 = *(const half8*)&qb[(m0 + l31) * 32 + 16 + hi * 8];

  f32x16 Z16 = {0,0,0,0,0,0,0,0,0,0,0,0,0,0,0,0};
  f32x16 acc0 = Z16, acc1 = Z16;
  float vsum = 0.f;

  // ---- V staging source (per-lane, private slice):
  //  lane stages rows (l>>2) of sub-slices i*16; 16B group qg (swizzle-matched)
  int qg = (l & 3) ^ ((l >> 3) & 3);
  const char* vp = (const char*)hb + (size_t)(c0 + (l >> 2)) * 8192 + qg * 16;

  // ---- K direct per-lane pointer (reg loads; +1024 u16 per tile) ----
  const u16* kp = kb + l31 * 32 + hi * 8;

  // ---- LDS read offsets within a buf (swizzle verbatim R4-proven) ----
  int sv = ((l31 >> 1) & 3) << 1;
  int va0 = l31 * 64 + (((0 + hi) ^ sv) * 8);
  int va1 = l31 * 64 + (((2 + hi) ^ sv) * 8);
  int va2 = l31 * 64 + (((4 + hi) ^ sv) * 8);
  int va3 = l31 * 64 + (((6 + hi) ^ sv) * 8);

  half8 kA0, kA1, kB0, kB1;

  // ---- prologue: V0, V1, K0->kA, V2 ; wait for V0 (10 ops after it) ----
  STAGEV(0)
  STAGEV(1)
  kA0 = *(const half8*)(kp);
  kA1 = *(const half8*)(kp + 16);
  STAGEV(2)
  VWAIT(10)

  // ---- main loop: bodies t=0..123 (unroll 2 for K reg slots) ----
  const u16* kpc = kp + 1024;     // K(1)
  for (int i2 = 0; i2 < 62; ++i2) {
    int tt = i2 * 2;
    // body(even t): cur kA, load K(t+1)->kB, stage V(t+3)
    kB0 = *(const half8*)(kpc);
    kB1 = *(const half8*)(kpc + 16);
    kpc += 1024;
    STAGEV((tt + 3) & 3)
    COMPUTE((tt & 3), kA0, kA1)
    VWAIT(12)
    // body(odd t): cur kB, load K(t+2)->kA, stage V(t+4)
    kA0 = *(const half8*)(kpc);
    kA1 = *(const half8*)(kpc + 16);
    kpc += 1024;
    STAGEV((tt + 4) & 3)
    COMPUTE(((tt + 1) & 3), kB0, kB1)
    VWAIT(12)
  }
  // body 124: cur kA, load K(125)->kB, stage V(127)
  kB0 = *(const half8*)(kpc);
  kB1 = *(const half8*)(kpc + 16);
  kpc += 1024;
  STAGEV(3)                        // (124+3)&3 = 3
  COMPUTE(0, kA0, kA1)             // 124&3 = 0
  VWAIT(12)
  // body 125: cur kB, load K(126)->kA, no stage
  kA0 = *(const half8*)(kpc);
  kA1 = *(const half8*)(kpc + 16);
  kpc += 1024;
  COMPUTE(1, kB0, kB1)
  VWAIT(8)
  // body 126: cur kA, load K(127)->kB
  kB0 = *(const half8*)(kpc);
  kB1 = *(const half8*)(kpc + 16);
  COMPUTE(2, kA0, kA1)
  VWAIT(4)
  // body 127: cur kB
  COMPUTE(3, kB0, kB1)

  // ---- epilogue: barrier-free normalize + write ----
  float vt = vsum + __shfl_xor(vsum, 32);
  float inv = 1.0f / vt;           // lane holds m = l31
  {
    float gamma = gam[0];
    const float* xb = xin + (size_t)b * 256 * 4096;
    float* ob = out + (size_t)b * 256 * 4096;
    f32x16 acc[2] = {acc0, acc1};
#pragma unroll
    for (int g = 0; g < 4; ++g) {
      float iv0 = __shfl(inv, 8 * g + 4 * hi + 0);
      float iv1 = __shfl(inv, 8 * g + 4 * hi + 1);
      float iv2 = __shfl(inv, 8 * g + 4 * hi + 2);
      float iv3 = __shfl(inv, 8 * g + 4 * hi + 3);
#pragma unroll
      for (int ct = 0; ct < 2; ++ct) {
        int c = c0 + ct * 32 + l31;
        size_t base = (size_t)c * 4096 + m0 + 8 * g + 4 * hi;
        float4 xv = *(const float4*)&xb[base];
        float4 ov;
        ov.x = gamma * acc[ct][4 * g + 0] * iv0 + xv.x;
        ov.y = gamma * acc[ct][4 * g + 1] * iv1 + xv.y;
        ov.z = gamma * acc[ct][4 * g + 2] * iv2 + xv.z;
        ov.w = gamma * acc[ct][4 * g + 3] * iv3 + xv.w;
        *(float4*)&ob[base] = ov;
      }
    }
  }
}

// ---------------------------------------------------------------------------
extern "C" void kernel_launch(void* const* d_in, const int* in_sizes, int n_in,
                              void* d_out, int out_size, void* d_ws, size_t ws_size,
                              hipStream_t stream)
{
  const float* x   = (const float*)d_in[0];
  const float* Wf  = (const float*)d_in[1];
  const float* bfp = (const float*)d_in[2];
  const float* Wg  = (const float*)d_in[3];
  const float* bgp = (const float*)d_in[4];
  const float* Wh  = (const float*)d_in[5];
  const float* bhp = (const float*)d_in[6];
  const float* gam = (const float*)d_in[7];
  float* out = (float*)d_out;

  char* ws = (char*)d_ws;
  u16*   xT   = (u16*)(ws);                  // 8,388,608 B  f16 [4][4096][256]
  u16*   Wall = (u16*)(ws + 8388608);        //   163,840 B  f16 [320][256]
  float* ball = (float*)(ws + 8552448);      //     2,048 B  f32 [320]
  u16*   q    = (u16*)(ws + 8554496);        // 2,097,152 B  f16 [4][4096][32]  (g, *log2e)
  u16*   km   = (u16*)(ws + 10651648);       // 2,097,152 B  f16 [4][4096][32]  (f)
  u16*   hbf  = (u16*)(ws + 12748800);       // 8,388,608 B  bf16 [4][256][4096] (h)

  k_prep<<<dim3(1104), dim3(256), 0, stream>>>(x, Wf, bfp, Wg, bgp, Wh, bhp, xT, Wall, ball);
  k_proj<<<dim3(1280), dim3(256), 0, stream>>>(xT, Wall, ball, q, km, hbf);
  k_attn<<<dim3(512),  dim3(256), 0, stream>>>(q, km, hbf, x, gam, out);
}